// Round 6
// baseline (103.146 us; speedup 1.0000x reference)
//
#include <hip/hip_runtime.h>

#define BATCH 4
#define SEQ   2048
#define EMB   128
#define NH    16
#define DK    8

// log2(e) / sqrt(8): fold softmax temperature into exp2 (pre-multiplied into qf)
#define QSCALE 0.510069726f

typedef _Float16 v4h  __attribute__((ext_vector_type(4)));
typedef _Float16 v8h  __attribute__((ext_vector_type(8)));
typedef __fp16   v2fp __attribute__((ext_vector_type(2)));
typedef float    v4f  __attribute__((ext_vector_type(4)));
typedef float    v16f __attribute__((ext_vector_type(16)));

// ---------------------------------------------------------------------------
// R21: R20 (dual-q) + trans/VALU exp split. Model (fits R15-R20): trans pipe
// accepts one wave64 v_exp_f32 per ~16 cyc => 256 of the ~337 cyc/chain-iter
// are exp throughput; chip floor 27us for 268M exps; attn measured 36us.
// Fix: per chain, 4 of 8 exp-pairs stay on trans, 4 move to full-rate packed
// f16 VALU via the R17-VALIDATED poly (passed harness, absmax unchanged) --
// but with v_pk_* FORCED by inline asm (R17's regression was clang
// scalarizing ext_vector f16 ops to ~30 instrs/pair; here 10/pair incl the
// pkrtz it replaces). Per chain-iter: trans 256->128 cyc, VALU +~72 cyc.
//
// Poly (t = score*log2e/sqrt8, |t|<=4.08):
//   t = cvt_pkrtz(s0,s1); m = t+1536 (RNE->int); n = m-1536 exact;
//   f = t-n exact in [-.5,.5]; p = deg-3(f); 2^n bits = (bits32(m) -
//   0x65F165F1) << 10 (no inter-half borrow/spill, HW-validated in R17).
//
// Structure otherwise identical to R20: each wave runs TWO q-chains against
// HALF the keys (kf/vt/addr/loop shared); partials additive, combined via
// 10 KB LDS. Layouts (HW-verified): S^T = mfma_32x32x16(A=K, B=Q^T); C/D
// col=L&31, row=(reg&3)+8(reg>>2)+4(L>>5); V^T key-perm (bits 2<->3) baked
// into F2 by feat_kernel; ones-row 8 = denominator; qf=0 on half1.
// ---------------------------------------------------------------------------

__launch_bounds__(256, 4)
__global__ void feat_kernel(const float* __restrict__ x,
                            const float* __restrict__ theta,
                            _Float16* __restrict__ F1,
                            _Float16* __restrict__ F2) {
  const int tid = threadIdx.x;
  const int bh  = blockIdx.x >> 3;          // 64 (b,h)
  const int s   = ((blockIdx.x & 7) << 8) + tid;
  const int b = bh >> 4, h = bh & 15;

  float th[8];
#pragma unroll
  for (int i = 0; i < 8; ++i) th[i] = theta[i];

  const float* xp = x + ((size_t)b * SEQ + s) * EMB + h * DK;
  const float4 a = *(const float4*)(xp);
  const float4 c = *(const float4*)(xp + 4);
  float r[8];
  r[0] = __cosf(a.x + th[0]);
  r[1] = r[0] * __cosf(a.y + th[1]);
  r[2] = r[1] * __cosf(a.z + th[2]);
  r[3] = r[2] * __cosf(a.w + th[3]);
  r[4] = r[3] * __cosf(c.x + th[4]);
  r[5] = r[4] * __cosf(c.y + th[5]);
  r[6] = r[5] * __cosf(c.z + th[6]);
  r[7] = r[6] * __cosf(c.w + th[7]);

  _Float16 hv[8];
#pragma unroll
  for (int i = 0; i < 8; ++i) hv[i] = (_Float16)r[i];

  // F1[bh][s][8]: 16 B contiguous store, s-consecutive lanes => coalesced
  union { v4h v[2]; float4 f; } u;
  u.v[0] = (v4h){hv[0], hv[1], hv[2], hv[3]};
  u.v[1] = (v4h){hv[4], hv[5], hv[6], hv[7]};
  *(float4*)(F1 + ((size_t)bh * SEQ + s) * 8) = u.f;

  // F2[bh][d][s_perm]: key-index bits 2<->3 swap baked in; per-d stores are
  // s-coalesced (permutation stays within each 16-group / 32 B)
  const int sp = (s & ~15) | (s & 3) | ((s & 4) << 1) | ((s & 8) >> 1);
  _Float16* f2 = F2 + (size_t)bh * 9 * SEQ;
#pragma unroll
  for (int d = 0; d < 8; ++d) f2[(size_t)d * SEQ + sp] = hv[d];
  f2[(size_t)8 * SEQ + s] = (_Float16)1.0f;   // denominator ones-row
}

// packed-f16 exp2 of a score pair, entirely on the full-rate VALU pipe.
// v_pk_* forced by inline asm (clang scalarizes ext_vector f16 arithmetic).
static __device__ __forceinline__ v2fp exp2_pk_valu(
    float a, float b, v2fp MAG, v2fp NEG1, v2fp C3, v2fp C2, v2fp C1, v2fp C0) {
  v2fp t = __builtin_amdgcn_cvt_pkrtz(a, b);
  v2fp m, n, f, p, r;
  asm("v_pk_add_f16 %0, %1, %2" : "=v"(m) : "v"(t), "v"(MAG));
  asm("v_pk_fma_f16 %0, %1, %2, %3" : "=v"(n) : "v"(MAG), "v"(NEG1), "v"(m));   // m-1536
  asm("v_pk_fma_f16 %0, %1, %2, %3" : "=v"(f) : "v"(n), "v"(NEG1), "v"(t));     // t-n
  asm("v_pk_fma_f16 %0, %1, %2, %3" : "=v"(p) : "v"(f), "v"(C3), "v"(C2));
  asm("v_pk_fma_f16 %0, %1, %2, %3" : "=v"(p) : "v"(f), "v"(p), "v"(C1));
  asm("v_pk_fma_f16 %0, %1, %2, %3" : "=v"(p) : "v"(f), "v"(p), "v"(C0));
  unsigned mb;
  __builtin_memcpy(&mb, &m, 4);
  const unsigned scb = (mb + 0x9A0E9A0Fu) << 10;   // (m - 0x65F165F1) << 10
  v2fp sc;
  __builtin_memcpy(&sc, &scb, 4);
  asm("v_pk_mul_f16 %0, %1, %2" : "=v"(r) : "v"(p), "v"(sc));
  return r;
}

__launch_bounds__(256, 4)
__global__ void attn_kernel(const _Float16* __restrict__ F1,
                            const _Float16* __restrict__ F2,
                            _Float16* __restrict__ Ah /* [B*S][128] f16 */) {
  __shared__ float P[4][2][5][64];          // 10 KB partial-combine buffer

  const int tid = threadIdx.x;
  const int L   = tid & 63;
  const int ln  = L & 31;
  const int hf  = L >> 5;                   // lane half
  const int wv  = tid >> 6;                 // wave 0..3
  const int pr  = wv >> 1;                  // q-pair 0..1
  const int kh  = wv & 1;                   // key half
  const int bh  = blockIdx.x >> 4;
  const int qbase = (blockIdx.x & 15) * 128;
  const int b = bh >> 4, h = bh & 15;
  const int mrow = (ln < 8) ? ln : 8;       // V^T row; ln>=8 -> ones-row 8

  // packed-f16 exp2 constants (deg-3, validated R17: harness passed)
#define H2(c) ((_Float16)(c))
  const v2fp MAG  = {H2(1536.0f), H2(1536.0f)};
  const v2fp NEG1 = {H2(-1.0f), H2(-1.0f)};
  const v2fp C3   = {H2(0.0559208f), H2(0.0559208f)};
  const v2fp C2   = {H2(0.2426315f), H2(0.2426315f)};
  const v2fp C1   = {H2(0.6931210f), H2(0.6931210f)};
  const v2fp C0   = {H2(1.0f), H2(1.0f)};

  const _Float16* f1 = F1 + (size_t)bh * SEQ * 8;
  const _Float16* kp = f1 + (size_t)(kh * 1024 + ln) * 8;   // this half's K rows
  const _Float16* vp = F2 + (size_t)bh * 9 * SEQ + (size_t)mrow * SEQ
                          + kh * 1024 + hf * 8;

  // two q-fragments (q-tiles 2*pr and 2*pr+1); half1 stays 0
  v8h qf0 = {0, 0, 0, 0, 0, 0, 0, 0};
  v8h qf1 = {0, 0, 0, 0, 0, 0, 0, 0};
  if (hf == 0) {
    const _Float16 qs = (_Float16)QSCALE;
    const v8h qsc = {qs, qs, qs, qs, qs, qs, qs, qs};
    qf0 = *(const v8h*)(f1 + (size_t)(qbase + pr * 64 + ln) * 8) * qsc;
    qf1 = *(const v8h*)(f1 + (size_t)(qbase + pr * 64 + 32 + ln) * 8) * qsc;
  }

  v16f acc0, acc1, zf;
#pragma unroll
  for (int i = 0; i < 16; ++i) { acc0[i] = 0.f; acc1[i] = 0.f; zf[i] = 0.f; }

  // ---- 32 K-tiles, dual chain, kf 1-deep prefetch ----
  v8h kf = *(const v8h*)kp; kp += 256;
#pragma unroll 4
  for (int kb = 0; kb < 32; ++kb) {
    const v8h kf_n = *(const v8h*)kp; kp += 256;   // next tile (pad-safe at end)
    const v16f s0 = __builtin_amdgcn_mfma_f32_32x32x16_f16(kf, qf0, zf, 0, 0, 0);
    const v16f s1 = __builtin_amdgcn_mfma_f32_32x32x16_f16(kf, qf1, zf, 0, 0, 0);
    const v8h vt0 = *(const v8h*)(vp);
    const v8h vt1 = *(const v8h*)(vp + 16); vp += 32;
    union { v2fp p[4]; v8h v; } a0, a1, b0, b1;
    // chain 0: pairs 0,1 on trans; pairs 2,3 on packed VALU
    a0.p[0] = __builtin_amdgcn_cvt_pkrtz(
        __builtin_amdgcn_exp2f(s0[0]), __builtin_amdgcn_exp2f(s0[1]));
    a0.p[1] = __builtin_amdgcn_cvt_pkrtz(
        __builtin_amdgcn_exp2f(s0[2]), __builtin_amdgcn_exp2f(s0[3]));
    a1.p[0] = __builtin_amdgcn_cvt_pkrtz(
        __builtin_amdgcn_exp2f(s0[8]), __builtin_amdgcn_exp2f(s0[9]));
    a1.p[1] = __builtin_amdgcn_cvt_pkrtz(
        __builtin_amdgcn_exp2f(s0[10]), __builtin_amdgcn_exp2f(s0[11]));
    a0.p[2] = exp2_pk_valu(s0[4],  s0[5],  MAG, NEG1, C3, C2, C1, C0);
    a0.p[3] = exp2_pk_valu(s0[6],  s0[7],  MAG, NEG1, C3, C2, C1, C0);
    a1.p[2] = exp2_pk_valu(s0[12], s0[13], MAG, NEG1, C3, C2, C1, C0);
    a1.p[3] = exp2_pk_valu(s0[14], s0[15], MAG, NEG1, C3, C2, C1, C0);
    acc0 = __builtin_amdgcn_mfma_f32_32x32x16_f16(vt0, a0.v, acc0, 0, 0, 0);
    acc0 = __builtin_amdgcn_mfma_f32_32x32x16_f16(vt1, a1.v, acc0, 0, 0, 0);
    // chain 1: same split
    b0.p[0] = __builtin_amdgcn_cvt_pkrtz(
        __builtin_amdgcn_exp2f(s1[0]), __builtin_amdgcn_exp2f(s1[1]));
    b0.p[1] = __builtin_amdgcn_cvt_pkrtz(
        __builtin_amdgcn_exp2f(s1[2]), __builtin_amdgcn_exp2f(s1[3]));
    b1.p[0] = __builtin_amdgcn_cvt_pkrtz(
        __builtin_amdgcn_exp2f(s1[8]), __builtin_amdgcn_exp2f(s1[9]));
    b1.p[1] = __builtin_amdgcn_cvt_pkrtz(
        __builtin_amdgcn_exp2f(s1[10]), __builtin_amdgcn_exp2f(s1[11]));
    b0.p[2] = exp2_pk_valu(s1[4],  s1[5],  MAG, NEG1, C3, C2, C1, C0);
    b0.p[3] = exp2_pk_valu(s1[6],  s1[7],  MAG, NEG1, C3, C2, C1, C0);
    b1.p[2] = exp2_pk_valu(s1[12], s1[13], MAG, NEG1, C3, C2, C1, C0);
    b1.p[3] = exp2_pk_valu(s1[14], s1[15], MAG, NEG1, C3, C2, C1, C0);
    acc1 = __builtin_amdgcn_mfma_f32_32x32x16_f16(vt0, b0.v, acc1, 0, 0, 0);
    acc1 = __builtin_amdgcn_mfma_f32_32x32x16_f16(vt1, b1.v, acc1, 0, 0, 0);
    kf = kf_n;
  }

  // ---- epilogue: combine key-half partials across the wave pair ----
  // acc C-layout: col=q=L&31, row=(reg&3)+8(reg>>2)+4*hf.
  // half0 regs 0-3 = dims 0-3, reg4 = row 8 = den; half1 regs 0-3 = dims 4-7.
#pragma unroll
  for (int r = 0; r < 5; ++r) {
    P[wv][0][r][L] = acc0[r];
    P[wv][1][r][L] = acc1[r];
  }
  __syncthreads();
  {
    const int p2 = (wv >> 1) << 1;      // pair base wave
    const int c  = wv & 1;              // this wave stores chain c => qtile wv
    float sum[4];
#pragma unroll
    for (int r = 0; r < 4; ++r) sum[r] = P[p2][c][r][L] + P[p2 + 1][c][r][L];
    const float den = P[p2][c][4][ln] + P[p2 + 1][c][4][ln];
    const float inv = 1.0f / den;
    const int qrow = qbase + wv * 32 + ln;
    v4h o = {(_Float16)(sum[0] * inv), (_Float16)(sum[1] * inv),
             (_Float16)(sum[2] * inv), (_Float16)(sum[3] * inv)};
    *(v4h*)(Ah + ((size_t)b * SEQ + qrow) * EMB + h * DK + hf * 4) = o;
  }
}

// ---------------------------------------------------------------------------
// MFMA projection (unchanged). out = Ah · W^T, fp32 out. W converted f32->f16
// during LDS staging; W row-major IS the B-fragment source. Block: 64 rows x
// 64 cols (grid 128x2), LDS 35 KB, 4 blocks/CU.
// ---------------------------------------------------------------------------
__launch_bounds__(256, 4)
__global__ void proj_kernel(const _Float16* __restrict__ Ah,
                            const float* __restrict__ W,
                            float* __restrict__ out) {
  __shared__ __align__(16) _Float16 Ahs[64][136];
  __shared__ __align__(16) _Float16 Whs[64][136];

  const int tid  = threadIdx.x;
  const int L    = tid & 63;
  const int wv   = tid >> 6;
  const int quad = L >> 4;
  const int ln   = L & 15;
  const int rowbase = blockIdx.x * 64;
  const int colbase = blockIdx.y * 64;

#pragma unroll
  for (int it = 0; it < 4; ++it) {
    const int idx = it * 256 + tid;
    const int r  = idx >> 4;
    const int c8 = idx & 15;
    *(uint4*)&Ahs[r][c8 * 8] =
        *(const uint4*)(Ah + (size_t)(rowbase + r) * EMB + c8 * 8);
  }
#pragma unroll
  for (int it = 0; it < 8; ++it) {
    const int idx = it * 256 + tid;
    const int n  = idx >> 5;
    const int c4 = idx & 31;
    const float4 w = *(const float4*)(W + (size_t)(colbase + n) * EMB + c4 * 4);
    v4h wh = {(_Float16)w.x, (_Float16)w.y, (_Float16)w.z, (_Float16)w.w};
    *(v4h*)&Whs[n][c4 * 4] = wh;
  }
  __syncthreads();

  v4f acc[4];
#pragma unroll
  for (int nt = 0; nt < 4; ++nt) acc[nt] = (v4f){0.f, 0.f, 0.f, 0.f};

#pragma unroll
  for (int k8 = 0; k8 < 8; ++k8) {
    const v4h af = *(const v4h*)&Ahs[wv * 16 + ln][k8 * 16 + quad * 4];
#pragma unroll
    for (int nt = 0; nt < 4; ++nt) {
      const v4h bf = *(const v4h*)&Whs[nt * 16 + ln][k8 * 16 + quad * 4];
      acc[nt] = __builtin_amdgcn_mfma_f32_16x16x16f16(af, bf, acc[nt], 0, 0, 0);
    }
  }

#pragma unroll
  for (int nt = 0; nt < 4; ++nt) {
    const int col = colbase + nt * 16 + ln;
#pragma unroll
    for (int r = 0; r < 4; ++r) {
      out[(size_t)(rowbase + wv * 16 + quad * 4 + r) * EMB + col] = acc[nt][r];
    }
  }
}

// ---------------------------------------------------------------------------
extern "C" void kernel_launch(void* const* d_in, const int* in_sizes, int n_in,
                              void* d_out, int out_size, void* d_ws, size_t ws_size,
                              hipStream_t stream) {
  const float* x     = (const float*)d_in[0];  // [4,2048,128]
  const float* theta = (const float*)d_in[1];  // [8]
  const float* w_out = (const float*)d_in[2];  // [128,128]
  float* out = (float*)d_out;                  // [4,2048,128]

  // workspace: Ah [8192][128] f16 (2 MB) | F1 [64][2048][8] f16 + 512-f16 pad
  // (kf prefetch overruns 1 tile = 512 B at the last iter) | F2 [64][9][2048]
  _Float16* Ah = (_Float16*)d_ws;
  _Float16* F1 = Ah + (size_t)BATCH * SEQ * EMB;
  _Float16* F2 = F1 + (size_t)64 * SEQ * 8 + 512;

  // features once, both layouts: 64 bh x 8 s-chunks = 512 blocks
  feat_kernel<<<dim3(512), dim3(256), 0, stream>>>(x, theta, F1, F2);

  // dual-q attention: 64 bh x 16 q-blocks = 1024 blocks, 4 waves
  attn_kernel<<<dim3(1024), dim3(256), 0, stream>>>(F1, F2, Ah);

  // projection: 128 row-tiles x 2 col-tiles
  proj_kernel<<<dim3((BATCH * SEQ) / 64, 2), dim3(256), 0, stream>>>(Ah, w_out, out);
}

// Round 7
// 94.997 us; speedup vs baseline: 1.0858x; 1.0858x over previous
//
#include <hip/hip_runtime.h>

#define BATCH 4
#define SEQ   2048
#define EMB   128
#define NH    16
#define DK    8

// log2(e) / sqrt(8): fold softmax temperature into exp2 (pre-multiplied into qf)
#define QSCALE 0.510069726f

typedef _Float16 v4h  __attribute__((ext_vector_type(4)));
typedef _Float16 v8h  __attribute__((ext_vector_type(8)));
typedef __fp16   v2fp __attribute__((ext_vector_type(2)));
typedef float    v4f  __attribute__((ext_vector_type(4)));
typedef float    v16f __attribute__((ext_vector_type(16)));

// ---------------------------------------------------------------------------
// R22 = R20 attn (reverted from R21) + overlapped proj.
// Model ledger: R17 & R21 both show removing trans exps saves ~0 while added
// VALU instrs cost full price => v_exp_f32 is HIDDEN (issue+latency of the
// non-exp stream is the binding resource). R20's shared-overhead
// amortization (dual-q) is the only lever that paid; attn inner loop is near
// its floor for this structure. This round banks the proj win instead:
// proj was 256 blocks = 1 block/CU = fully serial stage->sync->mfma->store;
// now 32-row tiles, grid 512 = 2 blocks/CU so phases overlap.
//
// attn structure (R20, HW-verified): each wave runs TWO q-chains (2 q-tiles)
// against HALF the keys; kf/vt/addr/loop shared across chains; plain-exp
// partials additive, combined via 10 KB LDS. S^T = mfma_32x32x16(A=K,B=Q^T);
// C/D col=L&31, row=(reg&3)+8(reg>>2)+4(L>>5). P=exp2(S^T) packs with pkrtz
// in natural order into the PV B-frag given the F2-baked key perm (bits
// 2<->3). qf=0 on half1 kills k=8..15 padding. Ones-row 8 = denominator.
// |score*log2e/sqrt8| <= 4.1 so plain exp exact.
// ---------------------------------------------------------------------------

__launch_bounds__(256, 4)
__global__ void feat_kernel(const float* __restrict__ x,
                            const float* __restrict__ theta,
                            _Float16* __restrict__ F1,
                            _Float16* __restrict__ F2) {
  const int tid = threadIdx.x;
  const int bh  = blockIdx.x >> 3;          // 64 (b,h)
  const int s   = ((blockIdx.x & 7) << 8) + tid;
  const int b = bh >> 4, h = bh & 15;

  float th[8];
#pragma unroll
  for (int i = 0; i < 8; ++i) th[i] = theta[i];

  const float* xp = x + ((size_t)b * SEQ + s) * EMB + h * DK;
  const float4 a = *(const float4*)(xp);
  const float4 c = *(const float4*)(xp + 4);
  float r[8];
  r[0] = __cosf(a.x + th[0]);
  r[1] = r[0] * __cosf(a.y + th[1]);
  r[2] = r[1] * __cosf(a.z + th[2]);
  r[3] = r[2] * __cosf(a.w + th[3]);
  r[4] = r[3] * __cosf(c.x + th[4]);
  r[5] = r[4] * __cosf(c.y + th[5]);
  r[6] = r[5] * __cosf(c.z + th[6]);
  r[7] = r[6] * __cosf(c.w + th[7]);

  _Float16 hv[8];
#pragma unroll
  for (int i = 0; i < 8; ++i) hv[i] = (_Float16)r[i];

  // F1[bh][s][8]: 16 B contiguous store, s-consecutive lanes => coalesced
  union { v4h v[2]; float4 f; } u;
  u.v[0] = (v4h){hv[0], hv[1], hv[2], hv[3]};
  u.v[1] = (v4h){hv[4], hv[5], hv[6], hv[7]};
  *(float4*)(F1 + ((size_t)bh * SEQ + s) * 8) = u.f;

  // F2[bh][d][s_perm]: key-index bits 2<->3 swap baked in; per-d stores are
  // s-coalesced (permutation stays within each 16-group / 32 B)
  const int sp = (s & ~15) | (s & 3) | ((s & 4) << 1) | ((s & 8) >> 1);
  _Float16* f2 = F2 + (size_t)bh * 9 * SEQ;
#pragma unroll
  for (int d = 0; d < 8; ++d) f2[(size_t)d * SEQ + sp] = hv[d];
  f2[(size_t)8 * SEQ + s] = (_Float16)1.0f;   // denominator ones-row
}

__launch_bounds__(256, 4)
__global__ void attn_kernel(const _Float16* __restrict__ F1,
                            const _Float16* __restrict__ F2,
                            _Float16* __restrict__ Ah /* [B*S][128] f16 */) {
  __shared__ float P[4][2][5][64];          // 10 KB partial-combine buffer

  const int tid = threadIdx.x;
  const int L   = tid & 63;
  const int ln  = L & 31;
  const int hf  = L >> 5;                   // lane half
  const int wv  = tid >> 6;                 // wave 0..3
  const int pr  = wv >> 1;                  // q-pair 0..1
  const int kh  = wv & 1;                   // key half
  const int bh  = blockIdx.x >> 4;
  const int qbase = (blockIdx.x & 15) * 128;
  const int b = bh >> 4, h = bh & 15;
  const int mrow = (ln < 8) ? ln : 8;       // V^T row; ln>=8 -> ones-row 8

  const _Float16* f1 = F1 + (size_t)bh * SEQ * 8;
  const _Float16* kp = f1 + (size_t)(kh * 1024 + ln) * 8;   // this half's K rows
  const _Float16* vp = F2 + (size_t)bh * 9 * SEQ + (size_t)mrow * SEQ
                          + kh * 1024 + hf * 8;

  // two q-fragments (q-tiles 2*pr and 2*pr+1); half1 stays 0
  v8h qf0 = {0, 0, 0, 0, 0, 0, 0, 0};
  v8h qf1 = {0, 0, 0, 0, 0, 0, 0, 0};
  if (hf == 0) {
    const _Float16 qs = (_Float16)QSCALE;
    const v8h qsc = {qs, qs, qs, qs, qs, qs, qs, qs};
    qf0 = *(const v8h*)(f1 + (size_t)(qbase + pr * 64 + ln) * 8) * qsc;
    qf1 = *(const v8h*)(f1 + (size_t)(qbase + pr * 64 + 32 + ln) * 8) * qsc;
  }

  v16f acc0, acc1, zf;
#pragma unroll
  for (int i = 0; i < 16; ++i) { acc0[i] = 0.f; acc1[i] = 0.f; zf[i] = 0.f; }

  // ---- 32 K-tiles, dual chain, kf 1-deep prefetch ----
  v8h kf = *(const v8h*)kp; kp += 256;
#pragma unroll 4
  for (int kb = 0; kb < 32; ++kb) {
    const v8h kf_n = *(const v8h*)kp; kp += 256;   // next tile (pad-safe at end)
    const v16f s0 = __builtin_amdgcn_mfma_f32_32x32x16_f16(kf, qf0, zf, 0, 0, 0);
    const v16f s1 = __builtin_amdgcn_mfma_f32_32x32x16_f16(kf, qf1, zf, 0, 0, 0);
    const v8h vt0 = *(const v8h*)(vp);
    const v8h vt1 = *(const v8h*)(vp + 16); vp += 32;
    union { v2fp p[4]; v8h v; } a0, a1, b0, b1;
#pragma unroll
    for (int i = 0; i < 4; ++i) {
      a0.p[i] = __builtin_amdgcn_cvt_pkrtz(
          __builtin_amdgcn_exp2f(s0[2 * i]),
          __builtin_amdgcn_exp2f(s0[2 * i + 1]));
      a1.p[i] = __builtin_amdgcn_cvt_pkrtz(
          __builtin_amdgcn_exp2f(s0[8 + 2 * i]),
          __builtin_amdgcn_exp2f(s0[8 + 2 * i + 1]));
    }
    acc0 = __builtin_amdgcn_mfma_f32_32x32x16_f16(vt0, a0.v, acc0, 0, 0, 0);
    acc0 = __builtin_amdgcn_mfma_f32_32x32x16_f16(vt1, a1.v, acc0, 0, 0, 0);
#pragma unroll
    for (int i = 0; i < 4; ++i) {
      b0.p[i] = __builtin_amdgcn_cvt_pkrtz(
          __builtin_amdgcn_exp2f(s1[2 * i]),
          __builtin_amdgcn_exp2f(s1[2 * i + 1]));
      b1.p[i] = __builtin_amdgcn_cvt_pkrtz(
          __builtin_amdgcn_exp2f(s1[8 + 2 * i]),
          __builtin_amdgcn_exp2f(s1[8 + 2 * i + 1]));
    }
    acc1 = __builtin_amdgcn_mfma_f32_32x32x16_f16(vt0, b0.v, acc1, 0, 0, 0);
    acc1 = __builtin_amdgcn_mfma_f32_32x32x16_f16(vt1, b1.v, acc1, 0, 0, 0);
    kf = kf_n;
  }

  // ---- epilogue: combine key-half partials across the wave pair ----
  // acc C-layout: col=q=L&31, row=(reg&3)+8(reg>>2)+4*hf.
  // half0 regs 0-3 = dims 0-3, reg4 = row 8 = den; half1 regs 0-3 = dims 4-7.
#pragma unroll
  for (int r = 0; r < 5; ++r) {
    P[wv][0][r][L] = acc0[r];
    P[wv][1][r][L] = acc1[r];
  }
  __syncthreads();
  {
    const int p2 = (wv >> 1) << 1;      // pair base wave
    const int c  = wv & 1;              // this wave stores chain c => qtile wv
    float sum[4];
#pragma unroll
    for (int r = 0; r < 4; ++r) sum[r] = P[p2][c][r][L] + P[p2 + 1][c][r][L];
    const float den = P[p2][c][4][ln] + P[p2 + 1][c][4][ln];
    const float inv = 1.0f / den;
    const int qrow = qbase + wv * 32 + ln;
    v4h o = {(_Float16)(sum[0] * inv), (_Float16)(sum[1] * inv),
             (_Float16)(sum[2] * inv), (_Float16)(sum[3] * inv)};
    *(v4h*)(Ah + ((size_t)b * SEQ + qrow) * EMB + h * DK + hf * 4) = o;
  }
}

// ---------------------------------------------------------------------------
// MFMA projection, R22: 32-row x 64-col tiles, grid (256,2) = 512 blocks =
// 2 blocks/CU (was 1) so the serial stage->sync->mfma->store chain of one
// block overlaps the other's. Waves remapped to 16-row x 32-col strips:
// row strip (wv&1)*16, col strip (wv>>1)*32, nt in {0,1}. Fragment math
// identical to the HW-verified original (only row/col offsets remapped).
// LDS 26.1 KB.
// ---------------------------------------------------------------------------
__launch_bounds__(256, 4)
__global__ void proj_kernel(const _Float16* __restrict__ Ah,
                            const float* __restrict__ W,
                            float* __restrict__ out) {
  __shared__ __align__(16) _Float16 Ahs[32][136];
  __shared__ __align__(16) _Float16 Whs[64][136];

  const int tid  = threadIdx.x;
  const int L    = tid & 63;
  const int wv   = tid >> 6;
  const int quad = L >> 4;
  const int ln   = L & 15;
  const int rowbase = blockIdx.x * 32;
  const int colbase = blockIdx.y * 64;

#pragma unroll
  for (int it = 0; it < 2; ++it) {
    const int idx = it * 256 + tid;     // 0..511 = 32 rows x 16 col-chunks
    const int r  = idx >> 4;
    const int c8 = idx & 15;
    *(uint4*)&Ahs[r][c8 * 8] =
        *(const uint4*)(Ah + (size_t)(rowbase + r) * EMB + c8 * 8);
  }
#pragma unroll
  for (int it = 0; it < 8; ++it) {
    const int idx = it * 256 + tid;
    const int n  = idx >> 5;
    const int c4 = idx & 31;
    const float4 w = *(const float4*)(W + (size_t)(colbase + n) * EMB + c4 * 4);
    v4h wh = {(_Float16)w.x, (_Float16)w.y, (_Float16)w.z, (_Float16)w.w};
    *(v4h*)&Whs[n][c4 * 4] = wh;
  }
  __syncthreads();

  const int rowoff = (wv & 1) * 16;
  const int coloff = (wv >> 1) * 32;

  v4f acc[2];
#pragma unroll
  for (int nt = 0; nt < 2; ++nt) acc[nt] = (v4f){0.f, 0.f, 0.f, 0.f};

#pragma unroll
  for (int k8 = 0; k8 < 8; ++k8) {
    const v4h af = *(const v4h*)&Ahs[rowoff + ln][k8 * 16 + quad * 4];
#pragma unroll
    for (int nt = 0; nt < 2; ++nt) {
      const v4h bf = *(const v4h*)&Whs[coloff + nt * 16 + ln][k8 * 16 + quad * 4];
      acc[nt] = __builtin_amdgcn_mfma_f32_16x16x16f16(af, bf, acc[nt], 0, 0, 0);
    }
  }

#pragma unroll
  for (int nt = 0; nt < 2; ++nt) {
    const int col = colbase + coloff + nt * 16 + ln;
#pragma unroll
    for (int r = 0; r < 4; ++r) {
      out[(size_t)(rowbase + rowoff + quad * 4 + r) * EMB + col] = acc[nt][r];
    }
  }
}

// ---------------------------------------------------------------------------
extern "C" void kernel_launch(void* const* d_in, const int* in_sizes, int n_in,
                              void* d_out, int out_size, void* d_ws, size_t ws_size,
                              hipStream_t stream) {
  const float* x     = (const float*)d_in[0];  // [4,2048,128]
  const float* theta = (const float*)d_in[1];  // [8]
  const float* w_out = (const float*)d_in[2];  // [128,128]
  float* out = (float*)d_out;                  // [4,2048,128]

  // workspace: Ah [8192][128] f16 (2 MB) | F1 [64][2048][8] f16 + 512-f16 pad
  // (kf prefetch overruns 1 tile = 512 B at the last iter) | F2 [64][9][2048]
  _Float16* Ah = (_Float16*)d_ws;
  _Float16* F1 = Ah + (size_t)BATCH * SEQ * EMB;
  _Float16* F2 = F1 + (size_t)64 * SEQ * 8 + 512;

  // features once, both layouts: 64 bh x 8 s-chunks = 512 blocks
  feat_kernel<<<dim3(512), dim3(256), 0, stream>>>(x, theta, F1, F2);

  // dual-q attention: 64 bh x 16 q-blocks = 1024 blocks, 4 waves
  attn_kernel<<<dim3(1024), dim3(256), 0, stream>>>(F1, F2, Ah);

  // projection: 256 row-tiles x 2 col-tiles = 512 blocks, 2/CU
  proj_kernel<<<dim3((BATCH * SEQ) / 32, 2), dim3(256), 0, stream>>>(Ah, w_out, out);
}